// Round 20
// baseline (364.888 us; speedup 1.0000x reference)
//
#include <hip/hip_runtime.h>
#include <math.h>

// Problem constants
#define KK     128
#define HH     384
#define H3     1152
#define PP     200
#define LL     50
#define VV     512
#define BB     256
#define II     16
#define NSTEPS 3

#define NT     1024    // 16 waves: 0-11 GRU split-K pairs (768 thr), 12-15 vals (256 thr)
#define GRUT   768
#define VP2    258     // vals float2 pitch
#define KQP    33      // keysq pitch (uints)

#define GIG    13      // i8 k-groups of 16 for w_ih (208/16, zero-padded)
// Coalesced slab layouts (thread tid = 2*gl + koff owns rows gl, gl+384, gl+768):
//  wqhh: uint4 idx (gg*3+s)*768 + tid ; gg<6 ; k-range = (koff*6+gg)*32 .. +32 (i4)
//  wqih: uint4 idx (gg*3+s)*768 + tid ; gg<7 ; group g = koff?7+gg:gg (zeros if g>=13) (i8)
#define WQ4H_UI (6 * 3 * 768 * 4)   // 55296 uints (221 KB)
#define WQI_UI  (7 * 3 * 768 * 4)   // 64512 uints (258 KB)

__device__ __forceinline__ int dot4(unsigned a, unsigned b, int c) {
    return __builtin_amdgcn_sdot4((int)a, (int)b, c, false);
}
__device__ __forceinline__ int dot8(unsigned a, unsigned b, int c) {
    return __builtin_amdgcn_sdot8((int)a, (int)b, c, false);
}
__device__ __forceinline__ float rcpf(float x) { return __builtin_amdgcn_rcpf(x); }
__device__ __forceinline__ float sigm(float x) { return rcpf(1.f + __expf(-x)); }
__device__ __forceinline__ float tanh_fast(float x) {
    float xc = fminf(fmaxf(x, -15.f), 15.f);
    float t = __expf(2.f * xc);
    return 1.f - 2.f * rcpf(t + 1.f);
}
__device__ __forceinline__ int q8(float x, float sc) {
    int q = (int)rintf(x * sc);
    return q < -127 ? -127 : (q > 127 ? 127 : q);
}
__device__ __forceinline__ int q4(float x, float sc) {
    int q = (int)rintf(x * sc);
    return q < -7 ? -7 : (q > 7 ? 7 : q);
}

// 12 dot8s of one k-group (rows gl, gl+384, gl+768)
#define GHDOT(hp, WA, WB, WC) do {                                    \
    ia0 = dot8((WA).x, (hp).x, ia0); ia0 = dot8((WA).y, (hp).y, ia0); \
    ia0 = dot8((WA).z, (hp).z, ia0); ia0 = dot8((WA).w, (hp).w, ia0); \
    ia1 = dot8((WB).x, (hp).x, ia1); ia1 = dot8((WB).y, (hp).y, ia1); \
    ia1 = dot8((WB).z, (hp).z, ia1); ia1 = dot8((WB).w, (hp).w, ia1); \
    ia2 = dot8((WC).x, (hp).x, ia2); ia2 = dot8((WC).y, (hp).y, ia2); \
    ia2 = dot8((WC).z, (hp).z, ia2); ia2 = dot8((WC).w, (hp).w, ia2); \
} while (0)

// Pass 1: global max|.| (order-independent)
__global__ void wmax_reduce(const float* __restrict__ w_hh,
                            const float* __restrict__ w_ih,
                            const float* __restrict__ prog_emb,
                            unsigned* __restrict__ scales)
{
    int idx = blockIdx.x * 256 + threadIdx.x;
    int stride = gridDim.x * 256;
    float mh = 0.f, mi = 0.f, mp = 0.f;
    for (int i = idx; i < HH * H3; i += stride) mh = fmaxf(mh, fabsf(w_hh[i]));
    for (int i = idx; i < PP * H3; i += stride) mi = fmaxf(mi, fabsf(w_ih[i]));
    for (int i = idx; i < 1000 * PP; i += stride) mp = fmaxf(mp, fabsf(prog_emb[i]));
    #pragma unroll
    for (int mm = 32; mm >= 1; mm >>= 1) {
        mh = fmaxf(mh, __shfl_xor(mh, mm, 64));
        mi = fmaxf(mi, __shfl_xor(mi, mm, 64));
        mp = fmaxf(mp, __shfl_xor(mp, mm, 64));
    }
    if ((threadIdx.x & 63) == 0) {
        atomicMax(scales,     __float_as_uint(mh));
        atomicMax(scales + 1, __float_as_uint(mi));
        atomicMax(scales + 2, __float_as_uint(mp));
    }
}

// Pass 2: coalesced split-K slab pack (same as r19)
__global__ void pack_weights(const float* __restrict__ w_hh,
                             const float* __restrict__ w_ih,
                             const unsigned* __restrict__ scales,
                             unsigned* __restrict__ wq)
{
    int idx = blockIdx.x * 256 + threadIdx.x;
    if (idx < WQ4H_UI) {
        const float sc = 7.f * rcpf(fmaxf(__uint_as_float(scales[0]), 1e-20f));
        int u4 = idx >> 2, m = idx & 3;
        int gg = u4 / (3 * 768);
        int r  = u4 - gg * (3 * 768);
        int s  = r / 768, tt = r - s * 768;
        int gl = tt >> 1, ko = tt & 1;
        int j = gl + 384 * s;
        int k = (ko * 6 + gg) * 32 + 8 * m;
        const float* wr = w_hh + (long)j * HH + k;
        unsigned pw = 0;
        #pragma unroll
        for (int e = 0; e < 8; ++e) pw |= ((unsigned)(q4(wr[e], sc) & 0xF)) << (4 * e);
        wq[idx] = pw;
    } else if (idx < WQ4H_UI + WQI_UI) {
        const float sc = 127.f * rcpf(fmaxf(__uint_as_float(scales[1]), 1e-20f));
        int q = idx - WQ4H_UI;
        int u4 = q >> 2, m = q & 3;
        int gg = u4 / (3 * 768);
        int r  = u4 - gg * (3 * 768);
        int s  = r / 768, tt = r - s * 768;
        int gl = tt >> 1, ko = tt & 1;
        int g = ko ? 7 + gg : gg;
        int j = gl + 384 * s;
        unsigned pw = 0;
        if (g < GIG) {
            int k = 16 * g + 4 * m;
            #pragma unroll
            for (int e = 0; e < 4; ++e) {
                float w = (k + e < PP) ? w_ih[(long)j * PP + k + e] : 0.f;
                pw |= ((unsigned)(q8(w, sc) & 255)) << (8 * e);
            }
        }
        wq[WQ4H_UI + u4 * 4 + m] = pw;
    }
}

struct __align__(16) Smem {
    float2 vals[LL * VP2];                                       // 103 KB
    unsigned keysq[LL * KQP + 16] __attribute__((aligned(16)));  // 6.7 KB
    unsigned hq4[2][48]     __attribute__((aligned(16)));
    unsigned hq8[2][96]     __attribute__((aligned(16)));
    unsigned progq[56]      __attribute__((aligned(16)));
    float  raw[4][52], wmw[4][52];
    float  rowoff[52];
    float  partial[4 * 52];
};  // ~112 KB

__global__ __attribute__((amdgpu_waves_per_eu(4, 4))) __launch_bounds__(NT)
void symop_main(const int* __restrict__ instr,
                const float* __restrict__ gate_emb,
                const float* __restrict__ program_emb,
                const float* __restrict__ primitive_emb,
                const uint4* __restrict__ wqhh,
                const uint4* __restrict__ wqih,
                const unsigned* __restrict__ scales,
                const float* __restrict__ b_ih,
                const float* __restrict__ b_hh,
                const float* __restrict__ keys_g,
                const float* __restrict__ init_value,
                float* __restrict__ out)
{
    __shared__ Smem sm;

    const int tid  = threadIdx.x;
    const int lane = tid & 63;
    const int wid  = tid >> 6;
    const int b    = blockIdx.x;
    const int gl   = tid >> 1;
    const int koff = tid & 1;

    const float maxH = fmaxf(__uint_as_float(scales[0]), 1e-20f);
    const float maxI = fmaxf(__uint_as_float(scales[1]), 1e-20f);
    const float maxP = fmaxf(__uint_as_float(scales[2]), 1e-20f);
    const float ghs = maxH * (1.f / 49.f);
    const float gis = maxI * maxP * (1.f / 16129.f);
    const float psc = 127.f * rcpf(maxP);
    const float lsc = 1.f / 16129.f;

    // ---- init ----
    float hcur = 0.f;
    if (tid < GRUT) hcur = keys_g[gl & 127];
    for (int idx = tid; idx < LL * 32; idx += NT) {
        int l = idx >> 5, kk = idx & 31;
        const float* kr = keys_g + l * KK + 4 * kk;
        unsigned pw = 0;
        #pragma unroll
        for (int e = 0; e < 4; ++e) pw |= ((unsigned)(q8(kr[e], 127.f) & 255)) << (8 * e);
        sm.keysq[l * KQP + kk] = pw;
    }
    if (tid < 96) {
        unsigned pw = 0;
        #pragma unroll
        for (int e = 0; e < 4; ++e) {
            int q = q8(keys_g[(4 * tid + e) & 127], 127.f);
            pw |= ((unsigned)(q & 255)) << (8 * e);
        }
        sm.hq8[0][tid] = pw;
    } else if (tid >= 128 && tid < 128 + 48) {
        int u = tid - 128;
        unsigned pw = 0;
        #pragma unroll
        for (int e = 0; e < 8; ++e) {
            int q = q4(keys_g[(8 * u + e) & 127], 7.f);
            pw |= ((unsigned)(q & 0xF)) << (4 * e);
        }
        sm.hq4[0][u] = pw;
    }
    for (int idx = tid; idx < LL * 256; idx += NT) {
        int l = idx >> 8, c = idx & 255;
        sm.vals[l * VP2 + c] = *(const float2*)(init_value + 2 * c);
    }
    if (tid >= GRUT && tid < GRUT + 52) {       // progq for word 0
        int qt = tid - GRUT;
        int w0 = instr[b];
        const float* pg = program_emb + (long)w0 * PP;
        unsigned pw = 0;
        #pragma unroll
        for (int e = 0; e < 4; ++e) {
            int k = 4 * qt + e;
            float v = (k < PP) ? pg[k] : 0.f;
            pw |= ((unsigned)(q8(v, psc) & 255)) << (8 * e);
        }
        sm.progq[qt] = pw;
    }
    __syncthreads();

    float bh0 = 0, bh1 = 0, bh2 = 0, bi0 = 0, bi1 = 0, bi2 = 0;
    // Register-resident w_hh slice: 18 named uint4 (72 VGPR), loaded ONCE.
    uint4 wA0, wB0, wC0, wA1, wB1, wC1, wA2, wB2, wC2,
          wA3, wB3, wC3, wA4, wB4, wC4, wA5, wB5, wC5;
    if (tid < GRUT) {
        bh0 = b_hh[gl]; bh1 = b_hh[gl + HH]; bh2 = b_hh[gl + 2 * HH];
        bi0 = b_ih[gl]; bi1 = b_ih[gl + HH]; bi2 = b_ih[gl + 2 * HH];
        const uint4* wp = wqhh + tid;
        wA0 = wp[0 * 768];  wB0 = wp[1 * 768];  wC0 = wp[2 * 768];
        wA1 = wp[3 * 768];  wB1 = wp[4 * 768];  wC1 = wp[5 * 768];
        wA2 = wp[6 * 768];  wB2 = wp[7 * 768];  wC2 = wp[8 * 768];
        wA3 = wp[9 * 768];  wB3 = wp[10 * 768]; wC3 = wp[11 * 768];
        wA4 = wp[12 * 768]; wB4 = wp[13 * 768]; wC4 = wp[14 * 768];
        wA5 = wp[15 * 768]; wB5 = wp[16 * 768]; wC5 = wp[17 * 768];
    }
    float gic0 = 0, gic1 = 0, gic2 = 0;
    float gnf0 = 0, gnf1 = 0, gnf2 = 0;

    // ---- prologue: gi(word0), split-K, coalesced ----
    if (tid < GRUT) {
        int ia0 = 0, ia1 = 0, ia2 = 0;
        const uint4* wi = wqih + tid;
        #pragma unroll 2
        for (int gg = 0; gg < 7; ++gg) {
            uint4 w0 = wi[(gg * 3 + 0) * 768];
            uint4 w1 = wi[(gg * 3 + 1) * 768];
            uint4 w2 = wi[(gg * 3 + 2) * 768];
            int g = koff ? 7 + gg : gg;
            uint4 hp = *(const uint4*)(sm.progq + 4 * ((g < GIG) ? g : 0));
            ia0 = dot4(w0.x, hp.x, ia0); ia0 = dot4(w0.y, hp.y, ia0);
            ia0 = dot4(w0.z, hp.z, ia0); ia0 = dot4(w0.w, hp.w, ia0);
            ia1 = dot4(w1.x, hp.x, ia1); ia1 = dot4(w1.y, hp.y, ia1);
            ia1 = dot4(w1.z, hp.z, ia1); ia1 = dot4(w1.w, hp.w, ia1);
            ia2 = dot4(w2.x, hp.x, ia2); ia2 = dot4(w2.y, hp.y, ia2);
            ia2 = dot4(w2.z, hp.z, ia2); ia2 = dot4(w2.w, hp.w, ia2);
        }
        ia0 += __shfl_xor(ia0, 1, 64);
        ia1 += __shfl_xor(ia1, 1, 64);
        ia2 += __shfl_xor(ia2, 1, 64);
        gic0 = bi0 + (float)ia0 * gis;
        gic1 = bi1 + (float)ia1 * gis;
        gic2 = bi2 + (float)ia2 * gis;
    }
    __syncthreads();   // protect progq: prologue read vs t==0 staging write

    int par = 0;
    for (int i = 0; i < II; ++i) {
        const int word = instr[i * BB + b];
        for (int t = 0; t < NSTEPS; ++t) {
            // ========== SINGLE PHASE ==========
            if (tid < GRUT) {
                // gh: i4 dot8 from REGISTER-RESIDENT weights + LDS hq4 broadcasts
                int ia0 = 0, ia1 = 0, ia2 = 0;
                const uint4* hb = (const uint4*)(sm.hq4[par] + koff * 24);
                { uint4 hp = hb[0]; GHDOT(hp, wA0, wB0, wC0); }
                { uint4 hp = hb[1]; GHDOT(hp, wA1, wB1, wC1); }
                { uint4 hp = hb[2]; GHDOT(hp, wA2, wB2, wC2); }
                { uint4 hp = hb[3]; GHDOT(hp, wA3, wB3, wC3); }
                { uint4 hp = hb[4]; GHDOT(hp, wA4, wB4, wC4); }
                { uint4 hp = hb[5]; GHDOT(hp, wA5, wB5, wC5); }
                ia0 += __shfl_xor(ia0, 1, 64);
                ia1 += __shfl_xor(ia1, 1, 64);
                ia2 += __shfl_xor(ia2, 1, 64);
                const float gh0 = bh0 + (float)ia0 * ghs;
                const float gh1 = bh1 + (float)ia1 * ghs;
                const float gh2 = bh2 + (float)ia2 * ghs;

                // next word's gi at t==1 (progq staged at t==0), both halves + combine
                if (t == 1 && i + 1 < II) {
                    int j0 = 0, j1 = 0, j2 = 0;
                    const uint4* wi = wqih + tid;
                    #pragma unroll 2
                    for (int gg = 0; gg < 7; ++gg) {
                        uint4 w0 = wi[(gg * 3 + 0) * 768];
                        uint4 w1 = wi[(gg * 3 + 1) * 768];
                        uint4 w2 = wi[(gg * 3 + 2) * 768];
                        int g = koff ? 7 + gg : gg;
                        uint4 hp = *(const uint4*)(sm.progq + 4 * ((g < GIG) ? g : 0));
                        j0 = dot4(w0.x, hp.x, j0); j0 = dot4(w0.y, hp.y, j0);
                        j0 = dot4(w0.z, hp.z, j0); j0 = dot4(w0.w, hp.w, j0);
                        j1 = dot4(w1.x, hp.x, j1); j1 = dot4(w1.y, hp.y, j1);
                        j1 = dot4(w1.z, hp.z, j1); j1 = dot4(w1.w, hp.w, j1);
                        j2 = dot4(w2.x, hp.x, j2); j2 = dot4(w2.y, hp.y, j2);
                        j2 = dot4(w2.z, hp.z, j2); j2 = dot4(w2.w, hp.w, j2);
                    }
                    j0 += __shfl_xor(j0, 1, 64);
                    j1 += __shfl_xor(j1, 1, 64);
                    j2 += __shfl_xor(j2, 1, 64);
                    gnf0 = bi0 + (float)j0 * gis;
                    gnf1 = bi1 + (float)j1 * gis;
                    gnf2 = bi2 + (float)j2 * gis;
                }

                // GRU (pair-duplicated; even threads write packs)
                const float r = sigm(gic0 + gh0);
                const float z = sigm(gic1 + gh1);
                const float n = tanh_fast(gic2 + r * gh2);
                const float hn = (1.f - z) * n + z * hcur;   // |hn| <= 1
                hcur = hn;
                int q8v = ((int)rintf(hn * 127.f)) & 255;
                unsigned v1 = (unsigned)q8v | ((unsigned)(__shfl_down(q8v, 2, 64) & 255) << 8);
                unsigned v2 = v1 | ((unsigned)__shfl_down((int)v1, 4, 64) << 16);
                if (!(tid & 7)) sm.hq8[par ^ 1][tid >> 3] = v2;
                int q4v = ((int)rintf(hn * 7.f)) & 0xF;
                unsigned u1 = (unsigned)q4v | ((unsigned)(__shfl_down(q4v, 2, 64) & 0xF) << 4);
                unsigned u2 = u1 | ((unsigned)(__shfl_down((int)u1, 4, 64) & 0xFF) << 8);
                unsigned u4 = u2 | ((unsigned)__shfl_down((int)u2, 8, 64) << 16);
                if (!(tid & 15)) sm.hq4[par ^ 1][tid >> 4] = u4;

                if (t == 2 && i + 1 < II) {
                    gic0 = gnf0; gic1 = gnf1; gic2 = gnf2;
                }
            } else {
                const int w4 = wid - 12;   // 0..3
                float rlog = -1e30f, wlog = -1e30f;
                if (lane < LL) {
                    int ir = 0, iw = 0;
                    const unsigned* kq = sm.keysq + lane * KQP;
                    const uint4* h8r = (const uint4*)(sm.hq8[par] + 32);
                    const uint4* h8w = (const uint4*)(sm.hq8[par] + 64);
                    #pragma unroll
                    for (int o = 0; o < 8; ++o) {
                        uint4 hr = h8r[o], hw = h8w[o];
                        unsigned k0 = kq[4 * o], k1 = kq[4 * o + 1];
                        unsigned k2 = kq[4 * o + 2], k3 = kq[4 * o + 3];
                        ir = dot4(k0, hr.x, ir); ir = dot4(k1, hr.y, ir);
                        ir = dot4(k2, hr.z, ir); ir = dot4(k3, hr.w, ir);
                        iw = dot4(k0, hw.x, iw); iw = dot4(k1, hw.y, iw);
                        iw = dot4(k2, hw.z, iw); iw = dot4(k3, hw.w, iw);
                    }
                    rlog = (float)ir * lsc;
                    wlog = (float)iw * lsc;
                }
                float mr = rlog, mw = wlog;
                #pragma unroll
                for (int mm = 32; mm >= 1; mm >>= 1) {
                    mr = fmaxf(mr, __shfl_xor(mr, mm, 64));
                    mw = fmaxf(mw, __shfl_xor(mw, mm, 64));
                }
                float er = (lane < LL) ? __expf(rlog - mr) : 0.f;
                float ew = (lane < LL) ? __expf(wlog - mw) : 0.f;
                float sr = er, sw = ew;
                #pragma unroll
                for (int mm = 32; mm >= 1; mm >>= 1) {
                    sr += __shfl_xor(sr, mm, 64);
                    sw += __shfl_xor(sw, mm, 64);
                }
                if (lane < LL) {
                    sm.raw[w4][lane] = er * rcpf(sr);
                    sm.wmw[w4][lane] = ew * rcpf(sw);
                }
                const float ge0 = gate_emb[2 * word], ge1 = gate_emb[2 * word + 1];
                const float gmx = fmaxf(ge0, ge1);
                const float e0 = __expf(ge0 - gmx), e1 = __expf(ge1 - gmx);
                const float g0 = e0 * rcpf(e0 + e1), g1 = 1.0f - g0;
                const float* prim = primitive_emb + (long)word * VV;

                const int c = tid - GRUT;   // 0..255
                float2 pr = *(const float2*)(prim + 2 * c);
                float rv0 = 0.f, rv1 = 0.f;
                #pragma unroll 10
                for (int l = 0; l < LL; ++l) {
                    float2 vv = sm.vals[l * VP2 + c];
                    rv0 = fmaf(sm.raw[w4][l], vv.x, rv0);
                    rv1 = fmaf(sm.raw[w4][l], vv.y, rv1);
                }
                const float nv0 = g0 * pr.x + g1 * rv0;
                const float nv1 = g0 * pr.y + g1 * rv1;
                #pragma unroll 10
                for (int l = 0; l < LL; ++l) {
                    float2 vv = sm.vals[l * VP2 + c];
                    const float w = sm.wmw[w4][l];
                    vv.x = fmaf(w, nv0 - vv.x, vv.x);
                    vv.y = fmaf(w, nv1 - vv.y, vv.y);
                    sm.vals[l * VP2 + c] = vv;
                }
                if (t == 0 && i + 1 < II && tid < GRUT + 52) {
                    int qt = tid - GRUT;
                    int wn = instr[(i + 1) * BB + b];
                    const float* pg = program_emb + (long)wn * PP;
                    unsigned pw = 0;
                    #pragma unroll
                    for (int e = 0; e < 4; ++e) {
                        int k = 4 * qt + e;
                        float v = (k < PP) ? pg[k] : 0.f;
                        pw |= ((unsigned)(q8(v, psc) & 255)) << (8 * e);
                    }
                    sm.progq[qt] = pw;
                }
            }
            __syncthreads();
            par ^= 1;
        }
    }

    // ---- epilogue ----
    if (tid < 256) {
        #pragma unroll 5
        for (int l = 0; l < LL; ++l) {
            float2 vv = sm.vals[l * VP2 + tid];
            float e = __expf(vv.x) + __expf(vv.y);
            #pragma unroll
            for (int mm = 32; mm >= 1; mm >>= 1) e += __shfl_xor(e, mm, 64);
            if (lane == 0) sm.partial[wid * 52 + l] = e;
        }
    }
    __syncthreads();
    if (tid < LL) {
        float s = 0.f;
        #pragma unroll
        for (int w = 0; w < 4; ++w) s += sm.partial[w * 52 + tid];
        sm.rowoff[tid] = logf(s);
    }
    __syncthreads();

    if (tid < 256) {
        float* ob0 = out + (long)b * VV * LL + (long)(2 * tid) * LL;
        float* ob1 = ob0 + LL;
        #pragma unroll 5
        for (int l = 0; l < LL; l += 2) {
            float2 va = sm.vals[l * VP2 + tid];
            float2 vb = sm.vals[(l + 1) * VP2 + tid];
            float o0 = sm.rowoff[l], o1 = sm.rowoff[l + 1];
            *(float2*)(ob0 + l) = make_float2(va.x - o0, vb.x - o1);
            *(float2*)(ob1 + l) = make_float2(va.y - o0, vb.y - o1);
        }
    }
}

__global__ void ta_copy(const int* __restrict__ ta, float* __restrict__ out2)
{
    int idx = blockIdx.x * 256 + threadIdx.x;
    if (idx < BB * LL) {
        int b2 = idx / LL, l = idx % LL;
        out2[idx] = (float)ta[l * BB + b2];
    }
}

extern "C" void kernel_launch(void* const* d_in, const int* in_sizes, int n_in,
                              void* d_out, int out_size, void* d_ws, size_t ws_size,
                              hipStream_t stream)
{
    const int*   instr        = (const int*)  d_in[0];
    const int*   true_actions = (const int*)  d_in[1];
    const float* gate_emb     = (const float*)d_in[2];
    const float* program_emb  = (const float*)d_in[3];
    const float* primitive_emb= (const float*)d_in[4];
    const float* w_ih         = (const float*)d_in[5];
    const float* w_hh         = (const float*)d_in[6];
    const float* b_ih         = (const float*)d_in[7];
    const float* b_hh         = (const float*)d_in[8];
    const float* scratch_keys = (const float*)d_in[9];
    const float* init_value   = (const float*)d_in[10];

    unsigned* scales = (unsigned*)d_ws;
    unsigned* wq     = (unsigned*)d_ws + 4;
    const uint4* wqhh = (const uint4*)wq;
    const uint4* wqih = (const uint4*)(wq + WQ4H_UI);

    hipMemsetAsync(scales, 0, 12, stream);
    wmax_reduce<<<256, 256, 0, stream>>>(w_hh, w_ih, program_emb, scales);
    {
        int total = WQ4H_UI + WQI_UI;
        pack_weights<<<(total + 255) / 256, 256, 0, stream>>>(w_hh, w_ih, scales, wq);
    }

    float* out = (float*)d_out;
    float* out_actions = out;
    float* out_ta      = out + (long)BB * VV * LL;

    symop_main<<<BB, NT, 0, stream>>>(instr, gate_emb, program_emb, primitive_emb,
                                      wqhh, wqih, scales, b_ih, b_hh,
                                      scratch_keys, init_value, out_actions);

    ta_copy<<<(BB * LL + 255) / 256, 256, 0, stream>>>(true_actions, out_ta);
}

// Round 21
// 302.514 us; speedup vs baseline: 1.2062x; 1.2062x over previous
//
#include <hip/hip_runtime.h>
#include <math.h>

// Problem constants
#define KK     128
#define HH     384
#define H3     1152
#define PP     200
#define LL     50
#define VV     512
#define BB     256
#define II     16
#define NSTEPS 3

#define NT     640     // 10 waves: 0-5 GRU/gh (384 thr), 6-9 vals (256 thr)
#define VP2    258     // vals float2 pitch
#define KQP    33      // keysq pitch (uints): bank (l+kk)%32 -> 2-way max

#define GH4G   12      // k-groups of 32 for w_hh (384/32), i4
#define GIG    13      // k-groups of 16 for w_ih (208/16, zero-padded), i8
#define WQ4H_UI (GH4G * 3 * 384 * 4)   // 55296 uints (221 KB, i4)
#define WQI_UI  (GIG  * 3 * 384 * 4)   // 59904 uints (240 KB, i8)

__device__ __forceinline__ int dot4(unsigned a, unsigned b, int c) {
    return __builtin_amdgcn_sdot4((int)a, (int)b, c, false);
}
__device__ __forceinline__ int dot8(unsigned a, unsigned b, int c) {
    return __builtin_amdgcn_sdot8((int)a, (int)b, c, false);
}
__device__ __forceinline__ float rcpf(float x) { return __builtin_amdgcn_rcpf(x); }
__device__ __forceinline__ float sigm(float x) { return rcpf(1.f + __expf(-x)); }
__device__ __forceinline__ float tanh_fast(float x) {
    float xc = fminf(fmaxf(x, -15.f), 15.f);
    float t = __expf(2.f * xc);
    return 1.f - 2.f * rcpf(t + 1.f);
}
__device__ __forceinline__ int q8(float x, float sc) {
    int q = (int)rintf(x * sc);
    return q < -127 ? -127 : (q > 127 ? 127 : q);
}
__device__ __forceinline__ int q4(float x, float sc) {
    int q = (int)rintf(x * sc);
    return q < -7 ? -7 : (q > 7 ? 7 : q);
}

// Pass 1: global max|.| for w_hh, w_ih, program_emb (order-independent)
__global__ void wmax_reduce(const float* __restrict__ w_hh,
                            const float* __restrict__ w_ih,
                            const float* __restrict__ prog_emb,
                            unsigned* __restrict__ scales)
{
    int idx = blockIdx.x * 256 + threadIdx.x;
    int stride = gridDim.x * 256;
    float mh = 0.f, mi = 0.f, mp = 0.f;
    for (int i = idx; i < HH * H3; i += stride) mh = fmaxf(mh, fabsf(w_hh[i]));
    for (int i = idx; i < PP * H3; i += stride) mi = fmaxf(mi, fabsf(w_ih[i]));
    for (int i = idx; i < 1000 * PP; i += stride) mp = fmaxf(mp, fabsf(prog_emb[i]));
    #pragma unroll
    for (int mm = 32; mm >= 1; mm >>= 1) {
        mh = fmaxf(mh, __shfl_xor(mh, mm, 64));
        mi = fmaxf(mi, __shfl_xor(mi, mm, 64));
        mp = fmaxf(mp, __shfl_xor(mp, mm, 64));
    }
    if ((threadIdx.x & 63) == 0) {
        atomicMax(scales,     __float_as_uint(mh));
        atomicMax(scales + 1, __float_as_uint(mi));
        atomicMax(scales + 2, __float_as_uint(mp));
    }
}

// Pass 2: slab pack.
__global__ void pack_weights(const float* __restrict__ w_hh,
                             const float* __restrict__ w_ih,
                             const unsigned* __restrict__ scales,
                             unsigned* __restrict__ wq)
{
    int idx = blockIdx.x * 256 + threadIdx.x;
    if (idx < WQ4H_UI) {
        const float sc = 7.f * rcpf(fmaxf(__uint_as_float(scales[0]), 1e-20f));
        int u4 = idx >> 2, m = idx & 3;
        int g = u4 / (3 * 384);
        int r = u4 - g * (3 * 384);
        int s = r / 384, t = r - s * 384;
        int j = t + 384 * s, k = 32 * g + 8 * m;
        const float* wr = w_hh + (long)j * HH + k;
        unsigned pw = 0;
        #pragma unroll
        for (int e = 0; e < 8; ++e) pw |= ((unsigned)(q4(wr[e], sc) & 0xF)) << (4 * e);
        wq[idx] = pw;
    } else if (idx < WQ4H_UI + WQI_UI) {
        const float sc = 127.f * rcpf(fmaxf(__uint_as_float(scales[1]), 1e-20f));
        int q = idx - WQ4H_UI;
        int u4 = q >> 2, m = q & 3;
        int g = u4 / (3 * 384);
        int r = u4 - g * (3 * 384);
        int s = r / 384, t = r - s * 384;
        int j = t + 384 * s, k = 16 * g + 4 * m;
        unsigned pw = 0;
        #pragma unroll
        for (int e = 0; e < 4; ++e) {
            float w = (k + e < PP) ? w_ih[(long)j * PP + k + e] : 0.f;
            pw |= ((unsigned)(q8(w, sc) & 255)) << (8 * e);
        }
        wq[WQ4H_UI + u4 * 4 + m] = pw;
    }
}

struct __align__(16) Smem {
    float2 vals[LL * VP2];                                   // 103 KB
    unsigned keysq[LL * KQP + 16] __attribute__((aligned(16)));  // 6.7 KB, i8 keys
    unsigned hq4[2][48]     __attribute__((aligned(16)));    // i4 h, ping-pong
    unsigned hq8[2][96]     __attribute__((aligned(16)));    // i8 h, ping-pong
    unsigned progq[56]      __attribute__((aligned(16)));
    float  raw[4][52], wmw[4][52];   // per-wave softmax outputs (waves 6-9)
    float  rowoff[52];
    float  partial[4 * 52];
};  // ~112 KB

__global__ __launch_bounds__(NT)
void symop_main(const int* __restrict__ instr,
                const float* __restrict__ gate_emb,
                const float* __restrict__ program_emb,
                const float* __restrict__ primitive_emb,
                const uint4* __restrict__ wqhh,
                const uint4* __restrict__ wqih,
                const unsigned* __restrict__ scales,
                const float* __restrict__ b_ih,
                const float* __restrict__ b_hh,
                const float* __restrict__ keys_g,
                const float* __restrict__ init_value,
                float* __restrict__ out)
{
    __shared__ Smem sm;

    const int tid  = threadIdx.x;
    const int lane = tid & 63;
    const int wid  = tid >> 6;
    const int b    = blockIdx.x;

    const float maxH = fmaxf(__uint_as_float(scales[0]), 1e-20f);
    const float maxI = fmaxf(__uint_as_float(scales[1]), 1e-20f);
    const float maxP = fmaxf(__uint_as_float(scales[2]), 1e-20f);
    const float ghs = maxH * (1.f / 49.f);
    const float gis = maxI * maxP * (1.f / 16129.f);
    const float psc = 127.f * rcpf(maxP);
    const float lsc = 1.f / 16129.f;          // logits scale (127*127)

    // ---- init ----
    float hcur = 0.f;
    if (tid < HH) hcur = keys_g[tid & 127];
    // keys -> i8 LDS (pitch 33)
    for (int idx = tid; idx < LL * 32; idx += NT) {
        int l = idx >> 5, kk = idx & 31;
        const float* kr = keys_g + l * KK + 4 * kk;
        unsigned pw = 0;
        #pragma unroll
        for (int e = 0; e < 4; ++e) pw |= ((unsigned)(q8(kr[e], 127.f) & 255)) << (8 * e);
        sm.keysq[l * KQP + kk] = pw;
    }
    if (tid < 96) {   // hq8[0]
        unsigned pw = 0;
        #pragma unroll
        for (int e = 0; e < 4; ++e) {
            int q = q8(keys_g[(4 * tid + e) & 127], 127.f);
            pw |= ((unsigned)(q & 255)) << (8 * e);
        }
        sm.hq8[0][tid] = pw;
    } else if (tid >= 128 && tid < 128 + 48) {   // hq4[0]
        int u = tid - 128;
        unsigned pw = 0;
        #pragma unroll
        for (int e = 0; e < 8; ++e) {
            int q = q4(keys_g[(8 * u + e) & 127], 7.f);
            pw |= ((unsigned)(q & 0xF)) << (4 * e);
        }
        sm.hq4[0][u] = pw;
    }
    for (int idx = tid; idx < LL * 256; idx += NT) {
        int l = idx >> 8, c = idx & 255;
        sm.vals[l * VP2 + c] = *(const float2*)(init_value + 2 * c);
    }
    if (tid >= 512 && tid < 512 + 52) {       // stage progq for word 0
        int qt = tid - 512;
        int w0 = instr[b];
        const float* pg = program_emb + (long)w0 * PP;
        unsigned pw = 0;
        #pragma unroll
        for (int e = 0; e < 4; ++e) {
            int k = 4 * qt + e;
            float v = (k < PP) ? pg[k] : 0.f;
            pw |= ((unsigned)(q8(v, psc) & 255)) << (8 * e);
        }
        sm.progq[qt] = pw;
    }
    __syncthreads();

    // biases (thread tid owns GRU lane tid: rows tid, tid+384, tid+768)
    float bh0 = 0, bh1 = 0, bh2 = 0, bi0 = 0, bi1 = 0, bi2 = 0;
    if (tid < HH) {
        bh0 = b_hh[tid]; bh1 = b_hh[tid + HH]; bh2 = b_hh[tid + 2 * HH];
        bi0 = b_ih[tid]; bi1 = b_ih[tid + HH]; bi2 = b_ih[tid + 2 * HH];
    }
    float gic0 = 0, gic1 = 0, gic2 = 0;
    int   gn0 = 0, gn1 = 0, gn2 = 0;

    // ---- prologue: gi(word0) on waves 0-5 (register-local) ----
    if (tid < HH) {
        int ia0 = 0, ia1 = 0, ia2 = 0;
        const uint4* wp = wqih + tid;
        #pragma unroll 2
        for (int g = 0; g < GIG; ++g) {
            uint4 w0 = wp[(g * 3 + 0) * 384];
            uint4 w1 = wp[(g * 3 + 1) * 384];
            uint4 w2 = wp[(g * 3 + 2) * 384];
            uint4 hp = *(const uint4*)(sm.progq + 4 * g);
            ia0 = dot4(w0.x, hp.x, ia0); ia0 = dot4(w0.y, hp.y, ia0);
            ia0 = dot4(w0.z, hp.z, ia0); ia0 = dot4(w0.w, hp.w, ia0);
            ia1 = dot4(w1.x, hp.x, ia1); ia1 = dot4(w1.y, hp.y, ia1);
            ia1 = dot4(w1.z, hp.z, ia1); ia1 = dot4(w1.w, hp.w, ia1);
            ia2 = dot4(w2.x, hp.x, ia2); ia2 = dot4(w2.y, hp.y, ia2);
            ia2 = dot4(w2.z, hp.z, ia2); ia2 = dot4(w2.w, hp.w, ia2);
        }
        gic0 = bi0 + (float)ia0 * gis;
        gic1 = bi1 + (float)ia1 * gis;
        gic2 = bi2 + (float)ia2 * gis;
    }
    // no barrier needed: main loop reads only init-barrier-protected state

    int par = 0;
    for (int i = 0; i < II; ++i) {
        const int word = instr[i * BB + b];
        for (int t = 0; t < NSTEPS; ++t) {
            // ========== SINGLE PHASE, single barrier ==========
            if (tid < HH) {
                // gh: i4 x i4 dot8 from hq4[par]
                int ia0 = 0, ia1 = 0, ia2 = 0;
                const uint4* wp = wqhh + tid;
                #pragma unroll 2
                for (int g = 0; g < GH4G; ++g) {
                    uint4 w0 = wp[(g * 3 + 0) * 384];
                    uint4 w1 = wp[(g * 3 + 1) * 384];
                    uint4 w2 = wp[(g * 3 + 2) * 384];
                    uint4 hp = *(const uint4*)(sm.hq4[par] + 4 * g);
                    ia0 = dot8(w0.x, hp.x, ia0); ia0 = dot8(w0.y, hp.y, ia0);
                    ia0 = dot8(w0.z, hp.z, ia0); ia0 = dot8(w0.w, hp.w, ia0);
                    ia1 = dot8(w1.x, hp.x, ia1); ia1 = dot8(w1.y, hp.y, ia1);
                    ia1 = dot8(w1.z, hp.z, ia1); ia1 = dot8(w1.w, hp.w, ia1);
                    ia2 = dot8(w2.x, hp.x, ia2); ia2 = dot8(w2.y, hp.y, ia2);
                    ia2 = dot8(w2.z, hp.z, ia2); ia2 = dot8(w2.w, hp.w, ia2);
                }
                const float gh0 = bh0 + (float)ia0 * ghs;
                const float gh1 = bh1 + (float)ia1 * ghs;
                const float gh2 = bh2 + (float)ia2 * ghs;

                // next word's gi in halves (progq staged at t==0, read t>=1)
                if (i + 1 < II) {
                    const uint4* wi = wqih + tid;
                    if (t == 1) {
                        gn0 = 0; gn1 = 0; gn2 = 0;
                        #pragma unroll 2
                        for (int g = 0; g < 7; ++g) {
                            uint4 w0 = wi[(g * 3 + 0) * 384];
                            uint4 w1 = wi[(g * 3 + 1) * 384];
                            uint4 w2 = wi[(g * 3 + 2) * 384];
                            uint4 hp = *(const uint4*)(sm.progq + 4 * g);
                            gn0 = dot4(w0.x, hp.x, gn0); gn0 = dot4(w0.y, hp.y, gn0);
                            gn0 = dot4(w0.z, hp.z, gn0); gn0 = dot4(w0.w, hp.w, gn0);
                            gn1 = dot4(w1.x, hp.x, gn1); gn1 = dot4(w1.y, hp.y, gn1);
                            gn1 = dot4(w1.z, hp.z, gn1); gn1 = dot4(w1.w, hp.w, gn1);
                            gn2 = dot4(w2.x, hp.x, gn2); gn2 = dot4(w2.y, hp.y, gn2);
                            gn2 = dot4(w2.z, hp.z, gn2); gn2 = dot4(w2.w, hp.w, gn2);
                        }
                    } else if (t == 2) {
                        #pragma unroll 2
                        for (int g = 7; g < GIG; ++g) {
                            uint4 w0 = wi[(g * 3 + 0) * 384];
                            uint4 w1 = wi[(g * 3 + 1) * 384];
                            uint4 w2 = wi[(g * 3 + 2) * 384];
                            uint4 hp = *(const uint4*)(sm.progq + 4 * g);
                            gn0 = dot4(w0.x, hp.x, gn0); gn0 = dot4(w0.y, hp.y, gn0);
                            gn0 = dot4(w0.z, hp.z, gn0); gn0 = dot4(w0.w, hp.w, gn0);
                            gn1 = dot4(w1.x, hp.x, gn1); gn1 = dot4(w1.y, hp.y, gn1);
                            gn1 = dot4(w1.z, hp.z, gn1); gn1 = dot4(w1.w, hp.w, gn1);
                            gn2 = dot4(w2.x, hp.x, gn2); gn2 = dot4(w2.y, hp.y, gn2);
                            gn2 = dot4(w2.z, hp.z, gn2); gn2 = dot4(w2.w, hp.w, gn2);
                        }
                    }
                }

                // GRU (register-local rows tid, tid+384, tid+768)
                const float r = sigm(gic0 + gh0);
                const float z = sigm(gic1 + gh1);
                const float n = tanh_fast(gic2 + r * gh2);
                const float hn = (1.f - z) * n + z * hcur;   // |hn| <= 1
                hcur = hn;
                // i8 pack -> hq8[par^1]
                int q8v = ((int)rintf(hn * 127.f)) & 255;
                unsigned v1 = (unsigned)q8v | ((unsigned)(__shfl_down(q8v, 1, 64) & 255) << 8);
                unsigned v2 = v1 | ((unsigned)__shfl_down((int)v1, 2, 64) << 16);
                if (!(tid & 3)) sm.hq8[par ^ 1][tid >> 2] = v2;
                // i4 pack -> hq4[par^1]
                int q4v = ((int)rintf(hn * 7.f)) & 0xF;
                unsigned u1 = (unsigned)q4v | ((unsigned)(__shfl_down(q4v, 1, 64) & 0xF) << 4);
                unsigned u2 = u1 | ((unsigned)(__shfl_down((int)u1, 2, 64) & 0xFF) << 8);
                unsigned u4 = u2 | ((unsigned)__shfl_down((int)u2, 4, 64) << 16);
                if (!(tid & 7)) sm.hq4[par ^ 1][tid >> 3] = u4;

                if (t == 2 && i + 1 < II) {
                    gic0 = bi0 + (float)gn0 * gis;
                    gic1 = bi1 + (float)gn1 * gis;
                    gic2 = bi2 + (float)gn2 * gis;
                }
            } else {
                const int w4 = wid - 6;   // 0..3
                // ---- i8 logits from keysq x hq8[par] (lane < 50, both dots) ----
                float rlog = -1e30f, wlog = -1e30f;
                if (lane < LL) {
                    int ir = 0, iw = 0;
                    const unsigned* kq = sm.keysq + lane * KQP;
                    const uint4* h8r = (const uint4*)(sm.hq8[par] + 32);
                    const uint4* h8w = (const uint4*)(sm.hq8[par] + 64);
                    #pragma unroll
                    for (int o = 0; o < 8; ++o) {
                        uint4 hr = h8r[o], hw = h8w[o];
                        unsigned k0 = kq[4 * o], k1 = kq[4 * o + 1];
                        unsigned k2 = kq[4 * o + 2], k3 = kq[4 * o + 3];
                        ir = dot4(k0, hr.x, ir); ir = dot4(k1, hr.y, ir);
                        ir = dot4(k2, hr.z, ir); ir = dot4(k3, hr.w, ir);
                        iw = dot4(k0, hw.x, iw); iw = dot4(k1, hw.y, iw);
                        iw = dot4(k2, hw.z, iw); iw = dot4(k3, hw.w, iw);
                    }
                    rlog = (float)ir * lsc;
                    wlog = (float)iw * lsc;
                }
                // ---- per-wave softmax ----
                float mr = rlog, mw = wlog;
                #pragma unroll
                for (int mm = 32; mm >= 1; mm >>= 1) {
                    mr = fmaxf(mr, __shfl_xor(mr, mm, 64));
                    mw = fmaxf(mw, __shfl_xor(mw, mm, 64));
                }
                float er = (lane < LL) ? __expf(rlog - mr) : 0.f;
                float ew = (lane < LL) ? __expf(wlog - mw) : 0.f;
                float sr = er, sw = ew;
                #pragma unroll
                for (int mm = 32; mm >= 1; mm >>= 1) {
                    sr += __shfl_xor(sr, mm, 64);
                    sw += __shfl_xor(sw, mm, 64);
                }
                if (lane < LL) {
                    sm.raw[w4][lane] = er * rcpf(sr);
                    sm.wmw[w4][lane] = ew * rcpf(sw);
                }
                // ---- gate ----
                const float ge0 = gate_emb[2 * word], ge1 = gate_emb[2 * word + 1];
                const float gmx = fmaxf(ge0, ge1);
                const float e0 = __expf(ge0 - gmx), e1 = __expf(ge1 - gmx);
                const float g0 = e0 * rcpf(e0 + e1), g1 = 1.0f - g0;
                const float* prim = primitive_emb + (long)word * VV;

                // ---- vals: thread owns exactly one float2 column ----
                const int c = tid - HH;   // 0..255
                float2 pr = *(const float2*)(prim + 2 * c);
                float rv0 = 0.f, rv1 = 0.f;
                #pragma unroll 10
                for (int l = 0; l < LL; ++l) {
                    float2 vv = sm.vals[l * VP2 + c];
                    rv0 = fmaf(sm.raw[w4][l], vv.x, rv0);
                    rv1 = fmaf(sm.raw[w4][l], vv.y, rv1);
                }
                const float nv0 = g0 * pr.x + g1 * rv0;
                const float nv1 = g0 * pr.y + g1 * rv1;
                #pragma unroll 10
                for (int l = 0; l < LL; ++l) {
                    float2 vv = sm.vals[l * VP2 + c];
                    const float w = sm.wmw[w4][l];
                    vv.x = fmaf(w, nv0 - vv.x, vv.x);
                    vv.y = fmaf(w, nv1 - vv.y, vv.y);
                    sm.vals[l * VP2 + c] = vv;
                }
                // ---- progq(word i+1) staging at t==0 (read after barrier, t>=1) ----
                if (t == 0 && i + 1 < II && tid >= 512 && tid < 512 + 52) {
                    int qt = tid - 512;
                    int wn = instr[(i + 1) * BB + b];
                    const float* pg = program_emb + (long)wn * PP;
                    unsigned pw = 0;
                    #pragma unroll
                    for (int e = 0; e < 4; ++e) {
                        int k = 4 * qt + e;
                        float v = (k < PP) ? pg[k] : 0.f;
                        pw |= ((unsigned)(q8(v, psc) & 255)) << (8 * e);
                    }
                    sm.progq[qt] = pw;
                }
            }
            __syncthreads();
            par ^= 1;
        }
    }

    // ---- epilogue: log-sum-exp per row (values bounded ~1 -> no max pass) ----
    if (tid < 256) {
        #pragma unroll 5
        for (int l = 0; l < LL; ++l) {
            float2 vv = sm.vals[l * VP2 + tid];
            float e = __expf(vv.x) + __expf(vv.y);
            #pragma unroll
            for (int mm = 32; mm >= 1; mm >>= 1) e += __shfl_xor(e, mm, 64);
            if (lane == 0) sm.partial[wid * 52 + l] = e;
        }
    }
    __syncthreads();
    if (tid < LL) {
        float s = 0.f;
        #pragma unroll
        for (int w = 0; w < 4; ++w) s += sm.partial[w * 52 + tid];
        sm.rowoff[tid] = logf(s);
    }
    __syncthreads();

    if (tid < 256) {
        float* ob0 = out + (long)b * VV * LL + (long)(2 * tid) * LL;
        float* ob1 = ob0 + LL;
        #pragma unroll 5
        for (int l = 0; l < LL; l += 2) {
            float2 va = sm.vals[l * VP2 + tid];
            float2 vb = sm.vals[(l + 1) * VP2 + tid];
            float o0 = sm.rowoff[l], o1 = sm.rowoff[l + 1];
            *(float2*)(ob0 + l) = make_float2(va.x - o0, vb.x - o1);
            *(float2*)(ob1 + l) = make_float2(va.y - o0, vb.y - o1);
        }
    }
}

__global__ void ta_copy(const int* __restrict__ ta, float* __restrict__ out2)
{
    int idx = blockIdx.x * 256 + threadIdx.x;
    if (idx < BB * LL) {
        int b2 = idx / LL, l = idx % LL;
        out2[idx] = (float)ta[l * BB + b2];
    }
}

extern "C" void kernel_launch(void* const* d_in, const int* in_sizes, int n_in,
                              void* d_out, int out_size, void* d_ws, size_t ws_size,
                              hipStream_t stream)
{
    const int*   instr        = (const int*)  d_in[0];
    const int*   true_actions = (const int*)  d_in[1];
    const float* gate_emb     = (const float*)d_in[2];
    const float* program_emb  = (const float*)d_in[3];
    const float* primitive_emb= (const float*)d_in[4];
    const float* w_ih         = (const float*)d_in[5];
    const float* w_hh         = (const float*)d_in[6];
    const float* b_ih         = (const float*)d_in[7];
    const float* b_hh         = (const float*)d_in[8];
    const float* scratch_keys = (const float*)d_in[9];
    const float* init_value   = (const float*)d_in[10];

    unsigned* scales = (unsigned*)d_ws;            // [0..2] maxima
    unsigned* wq     = (unsigned*)d_ws + 4;        // 16B-aligned slabs
    const uint4* wqhh = (const uint4*)wq;
    const uint4* wqih = (const uint4*)(wq + WQ4H_UI);

    hipMemsetAsync(scales, 0, 12, stream);
    wmax_reduce<<<256, 256, 0, stream>>>(w_hh, w_ih, program_emb, scales);
    {
        int total = WQ4H_UI + WQI_UI;
        pack_weights<<<(total + 255) / 256, 256, 0, stream>>>(w_hh, w_ih, scales, wq);
    }

    float* out = (float*)d_out;
    float* out_actions = out;
    float* out_ta      = out + (long)BB * VV * LL;

    symop_main<<<BB, NT, 0, stream>>>(instr, gate_emb, program_emb, primitive_emb,
                                      wqhh, wqih, scales, b_ih, b_hh,
                                      scratch_keys, init_value, out_actions);

    ta_copy<<<(BB * LL + 255) / 256, 256, 0, stream>>>(true_actions, out_ta);
}